// Round 19
// baseline (140.397 us; speedup 1.0000x reference)
//
#include <hip/hip_runtime.h>
#include <stdint.h>

#define DIMF   1024
#define HEADS  16
#define HD     64
#define BB     2
#define NN     2048
#define NKP    2112   // 2049 keys padded to 33*64
#define NTILE  33

typedef __attribute__((ext_vector_type(8))) __bf16 bf16x8;
typedef __attribute__((ext_vector_type(4))) float  f32x4;

__device__ __forceinline__ float b2f(uint16_t h) {
  union { uint32_t u; float f; } v; v.u = ((uint32_t)h) << 16; return v.f;
}
__device__ __forceinline__ uint16_t f2b(float f) {
  union { float f; uint32_t u; } v; v.f = f;
  uint32_t r = v.u + 0x7FFFu + ((v.u >> 16) & 1u);
  return (uint16_t)(r >> 16);
}

// async global->LDS DMA, 16B per lane. LDS dest = wave-uniform base + lane*16.
__device__ __forceinline__ void gl_lds16(const void* g, void* l) {
  __builtin_amdgcn_global_load_lds(
      (const __attribute__((address_space(1))) void*)g,
      (__attribute__((address_space(3))) void*)l, 16, 0, 0);
}

// ---- merged preprocessing (single launch) — EXACT round-16 kernel ----
__global__ __launch_bounds__(256) void prep_k(const float* __restrict__ x,
                                              uint16_t* __restrict__ x_bf,
                                              const float* __restrict__ vk,
                                              const float* __restrict__ vv,
                                              uint16_t* __restrict__ k_ws,
                                              uint16_t* __restrict__ vt_ws,
                                              const float* __restrict__ wqkv,
                                              uint16_t* __restrict__ wqkvT,
                                              const float* __restrict__ wout,
                                              uint16_t* __restrict__ woutT) {
  __shared__ uint16_t tile[32][33];
  const int blk = blockIdx.x;
  if (blk < 4096) {
    int i = blk * 256 + threadIdx.x;             // < 1048576 float4s
    float4 v = *(const float4*)&x[(size_t)i * 4];
    uint16_t* d = x_bf + (size_t)i * 4;
    d[0] = f2b(v.x); d[1] = f2b(v.y); d[2] = f2b(v.z); d[3] = f2b(v.w);
  } else if (blk < 4608) {
    int idx = (blk - 4096) * 256 + threadIdx.x;  // 0 .. 131071
    int dd = idx & 63;
    int r  = (idx >> 6) & 63;      // padded key row 2048+r
    int bh = idx >> 12;            // 0..31
    int h  = bh & (HEADS - 1);
    uint16_t kv  = (r == 0) ? f2b(vk[h * HD + dd]) : (uint16_t)0;
    uint16_t vvv = (r == 0) ? f2b(vv[h * HD + dd]) : (uint16_t)0;
    k_ws[((size_t)bh * NKP + NN + r) * HD + dd]  = kv;
    vt_ws[((size_t)bh * HD + dd) * NKP + NN + r] = vvv;
  } else {
    int tb = blk - 4608;
    const float* src; uint16_t* dst; int N, bx, by;
    if (tb < 3072) { src = wqkv; dst = wqkvT; N = 3072; bx = (tb % 96) * 32; by = (tb / 96) * 32; }
    else { tb -= 3072; src = wout; dst = woutT; N = 1024; bx = (tb % 32) * 32; by = (tb / 32) * 32; }
    const int M = 1024;
    int xx = threadIdx.x & 31, y0 = (threadIdx.x >> 5) * 4;
#pragma unroll
    for (int i = 0; i < 4; ++i)
      tile[y0 + i][xx] = f2b(src[(size_t)(by + y0 + i) * N + bx + xx]);
    __syncthreads();
#pragma unroll
    for (int i = 0; i < 4; ++i)
      dst[(size_t)(bx + y0 + i) * M + by + xx] = tile[xx][y0 + i];
  }
}

// ------------- GEMM0: 128x128, BK=64, swizzled (round-16 proven structure) -------------
// NEW: Q outputs pre-scaled by per-head (dim^-0.5/temp)*log2e. which/h are
// WAVE-UNIFORM (ng spans 64 cols within one 64-block), so qsW is computed once
// per thread (2 scalar loads + 1 divide) — avoids r17's per-element load bug.
__global__ __launch_bounds__(256) void gemm0_k(const uint16_t* __restrict__ A,
                                               const uint16_t* __restrict__ Bt,
                                               int K,
                                               uint16_t* __restrict__ o0,
                                               uint16_t* __restrict__ o1,
                                               uint16_t* __restrict__ o2,
                                               const float* __restrict__ trace,
                                               const float* __restrict__ factor) {
  __shared__ uint16_t lds_a[128][64];   // 16 KB, linear dest for global_load_lds
  __shared__ uint16_t lds_b[128][64];   // 16 KB
  const int m0 = blockIdx.y * 128, n0 = blockIdx.x * 128;
  const int tid = threadIdx.x, lane = tid & 63, wid = tid >> 6;
  const int wm = (wid >> 1) * 64, wn = (wid & 1) * 64;
  const int lr = lane & 15, lg = lane >> 4;

  const int rsw = (lr & 7) << 4;
  const int rc0 = (lg * 16) ^ rsw;
  const int rc1 = (64 + lg * 16) ^ rsw;

  f32x4 acc[4][4] = {};
  for (int k0 = 0; k0 < K; k0 += 64) {
    __syncthreads();
#pragma unroll
    for (int it = 0; it < 4; ++it) {
      const int chunk = wid * 4 + it;            // 0..15 (1 KiB each)
      const int o = chunk * 1024 + lane * 16;
      const int r = o >> 7, cb = o & 127;        // 128 B per row
      const int scb = cb ^ ((r & 7) << 4);       // pre-swizzled source col
      gl_lds16((const char*)&A[(size_t)(m0 + r) * K + k0] + scb,
               (char*)&lds_a[0][0] + chunk * 1024);
      gl_lds16((const char*)&Bt[(size_t)(n0 + r) * K + k0] + scb,
               (char*)&lds_b[0][0] + chunk * 1024);
    }
    __syncthreads();
    bf16x8 af[4][2], bf[4][2];
#pragma unroll
    for (int i = 0; i < 4; ++i) {
      const char* ra = (const char*)&lds_a[0][0] + (wm + i * 16 + lr) * 128;
      af[i][0] = *(const bf16x8*)(ra + rc0);
      af[i][1] = *(const bf16x8*)(ra + rc1);
    }
#pragma unroll
    for (int j = 0; j < 4; ++j) {
      const char* rb = (const char*)&lds_b[0][0] + (wn + j * 16 + lr) * 128;
      bf[j][0] = *(const bf16x8*)(rb + rc0);
      bf[j][1] = *(const bf16x8*)(rb + rc1);
    }
#pragma unroll
    for (int kk = 0; kk < 2; ++kk)
#pragma unroll
      for (int i = 0; i < 4; ++i)
#pragma unroll
        for (int j = 0; j < 4; ++j)
          acc[i][j] = __builtin_amdgcn_mfma_f32_16x16x32_bf16(af[i][kk], bf[j][kk],
                                                              acc[i][j], 0, 0, 0);
  }
  // which/h are uniform over this wave's 64-column span
  const int ngb    = n0 + wn;
  const int whichU = ngb >> 10;
  const int hU     = (ngb & (DIMF - 1)) >> 6;
  float qsW = 1.0f;
  if (whichU == 0)
    qsW = 0.04508422f / fmaxf(1.0f + fabsf(trace[hU]) * factor[hU], 1.0f);
#pragma unroll
  for (int i = 0; i < 4; ++i)
#pragma unroll
    for (int j = 0; j < 4; ++j)
#pragma unroll
      for (int r = 0; r < 4; ++r) {
        int mg = m0 + wm + i * 16 + lg * 4 + r;   // C row = m (m89 layout)
        int ng = n0 + wn + j * 16 + lr;            // C col = n
        int b = mg >> 11, n = mg & (NN - 1);
        int dd = ng & 63;
        int bh = b * HEADS + hU;
        float v = acc[i][j][r];
        if (whichU == 0)      o0[((size_t)bh * NN + n) * HD + dd] = f2b(v * qsW);
        else if (whichU == 1) o1[((size_t)bh * NKP + n) * HD + dd] = f2b(v);
        else                  o2[((size_t)bh * HD + dd) * NKP + n] = f2b(v);  // V^T
      }
}

// ------------- GEMM1 — EXACT round-16 kernel (BM=64, BN=128) -------------
__global__ __launch_bounds__(256) void gemm1_k(const uint16_t* __restrict__ A,
                                               const uint16_t* __restrict__ Bt,
                                               int K,
                                               float* __restrict__ fo,
                                               const float* __restrict__ bias) {
  __shared__ uint16_t lds_a[64][64];    // 8 KB
  __shared__ uint16_t lds_b[128][64];   // 16 KB
  const int m0 = blockIdx.y * 64, n0 = blockIdx.x * 128;
  const int tid = threadIdx.x, lane = tid & 63, wid = tid >> 6;
  const int wm = (wid >> 1) * 32, wn = (wid & 1) * 64;
  const int lr = lane & 15, lg = lane >> 4;

  const int rsw = (lr & 7) << 4;
  const int rc0 = (lg * 16) ^ rsw;
  const int rc1 = (64 + lg * 16) ^ rsw;

  f32x4 acc[2][4] = {};
  for (int k0 = 0; k0 < K; k0 += 64) {
    __syncthreads();
#pragma unroll
    for (int it = 0; it < 6; ++it) {
      const int c = wid * 6 + it;                // 0..23 (1 KiB each): 8 A + 16 B
      if (c < 8) {
        const int o = c * 1024 + lane * 16;
        const int r = o >> 7, cb = o & 127;
        const int scb = cb ^ ((r & 7) << 4);
        gl_lds16((const char*)&A[(size_t)(m0 + r) * K + k0] + scb,
                 (char*)&lds_a[0][0] + c * 1024);
      } else {
        const int o2 = (c - 8) * 1024 + lane * 16;
        const int r = o2 >> 7, cb = o2 & 127;
        const int scb = cb ^ ((r & 7) << 4);
        gl_lds16((const char*)&Bt[(size_t)(n0 + r) * K + k0] + scb,
                 (char*)&lds_b[0][0] + (c - 8) * 1024);
      }
    }
    __syncthreads();
    bf16x8 af[2][2], bf[4][2];
#pragma unroll
    for (int i = 0; i < 2; ++i) {
      const char* ra = (const char*)&lds_a[0][0] + (wm + i * 16 + lr) * 128;
      af[i][0] = *(const bf16x8*)(ra + rc0);
      af[i][1] = *(const bf16x8*)(ra + rc1);
    }
#pragma unroll
    for (int j = 0; j < 4; ++j) {
      const char* rb = (const char*)&lds_b[0][0] + (wn + j * 16 + lr) * 128;
      bf[j][0] = *(const bf16x8*)(rb + rc0);
      bf[j][1] = *(const bf16x8*)(rb + rc1);
    }
#pragma unroll
    for (int kk = 0; kk < 2; ++kk)
#pragma unroll
      for (int i = 0; i < 2; ++i)
#pragma unroll
        for (int j = 0; j < 4; ++j)
          acc[i][j] = __builtin_amdgcn_mfma_f32_16x16x32_bf16(af[i][kk], bf[j][kk],
                                                              acc[i][j], 0, 0, 0);
  }
#pragma unroll
  for (int i = 0; i < 2; ++i)
#pragma unroll
    for (int j = 0; j < 4; ++j)
#pragma unroll
      for (int r = 0; r < 4; ++r) {
        int mg = m0 + wm + i * 16 + lg * 4 + r;
        int ng = n0 + wn + j * 16 + lr;
        fo[(size_t)mg * DIMF + ng] = acc[i][j][r] + bias[ng];
      }
}

// ---- flash attention: round-18 dbuf kernel + exp2 (Q pre-scaled) + ldsp swizzle ----
// Changes vs r18: (1) no per-head scale in-kernel (Q carries scale*log2e from
// gemm0) -> p = exp2f(s), 16 fewer v_mul/tile; (2) ldsp is [8][16][64] with the
// T2 XOR swizzle (byte ^= (row&7)<<4 on both write and read) -> pf reads go
// 4-way-conflict -> free, LDS 51.2 -> 48 KB. Everything else byte-identical.
__global__ __launch_bounds__(512) void attn_k(const uint16_t* __restrict__ q_ws,
                                              const uint16_t* __restrict__ k_ws,
                                              const uint16_t* __restrict__ vt_ws,
                                              uint16_t* __restrict__ o_ws) {
  __shared__ uint16_t ldsk[2][64][64];   // [buf][key][d], swizzled cols (16 KB)
  __shared__ uint16_t ldsv[2][64][64];   // [buf][d][key], swizzled cols (16 KB)
  __shared__ uint16_t ldsp[8][16][64];   // [wave][q][key], XOR-swizzled (16 KB)
  const int bh = blockIdx.x;             // FASTEST dim -> XCD = bh%8 (L2 locality)
  const int qb = blockIdx.y;
  const int h = bh & (HEADS - 1), b = bh >> 4;
  const int tid = threadIdx.x, lane = tid & 63, wid = tid >> 6;  // wid 0..7
  const int lr = lane & 15, lg = lane >> 4;

  const int qrow0 = qb * 128 + wid * 16;
  const uint16_t* qrow = q_ws + ((size_t)bh * NN + qrow0 + lr) * HD;
  bf16x8 qf[2];
  qf[0] = *(const bf16x8*)(qrow + lg * 8);
  qf[1] = *(const bf16x8*)(qrow + 32 + lg * 8);

  // hoisted loop-invariant LDS read offsets (row = c*16+lr -> row&7 == lr&7)
  const int rsw = (lr & 7) << 4;
  const int kb0 = lr * 128 + ((lg * 16) ^ rsw);
  const int kb1 = lr * 128 + ((64 + lg * 16) ^ rsw);
  const char* kbase = (const char*)&ldsk[0][0][0];
  const char* vbase = (const char*)&ldsv[0][0][0];
  // ldsp: row q=lr (128 B rows), byte ^= (lr&7)<<4 = rsw
  const char* pr0 = (const char*)&ldsp[wid][lr][0] + ((lg * 16) ^ rsw);
  const char* pr1 = (const char*)&ldsp[wid][lr][0] + ((64 + lg * 16) ^ rsw);

  f32x4 acc[4] = {};
  float lsum[4] = {0.f, 0.f, 0.f, 0.f};

#define STAGE(buf, t)                                                            \
  {                                                                              \
    const int t0_ = (t) * 64;                                                    \
    const int chunk = wid;                    /* 0..7 (1 KiB each) */            \
    const int o = chunk * 1024 + lane * 16;                                      \
    const int r = o >> 7, cb = o & 127;       /* 128 B per row */                \
    const int scb = cb ^ ((r & 7) << 4);      /* pre-swizzled source col */      \
    gl_lds16((const char*)&k_ws[((size_t)bh * NKP + t0_ + r) * HD] + scb,        \
             (char*)&ldsk[buf][0][0] + chunk * 1024);                            \
    gl_lds16((const char*)&vt_ws[((size_t)bh * HD + r) * NKP + t0_] + scb,       \
             (char*)&ldsv[buf][0][0] + chunk * 1024);                            \
  }

  STAGE(0, 0);
  __syncthreads();   // vmcnt(0) drained: tile 0 visible
  int cur = 0;

  for (int t = 0; t < NTILE; ++t) {
    const int tn = (t + 1 < NTILE) ? t + 1 : t;  // last iter: harmless restage
    STAGE(cur ^ 1, tn);                          // issue BEFORE compute

    const int koff = cur * 8192;                 // byte offset of current buffer

    // S = Q K^T (4 chunks of 16 keys); Q pre-scaled by scale*log2e
    f32x4 s[4];
#pragma unroll
    for (int c = 0; c < 4; ++c) {
      bf16x8 kf0 = *(const bf16x8*)(kbase + koff + kb0 + c * 2048);
      bf16x8 kf1 = *(const bf16x8*)(kbase + koff + kb1 + c * 2048);
      f32x4 sa = {};
      __builtin_amdgcn_s_setprio(1);
      sa = __builtin_amdgcn_mfma_f32_16x16x32_bf16(qf[0], kf0, sa, 0, 0, 0);
      sa = __builtin_amdgcn_mfma_f32_16x16x32_bf16(qf[1], kf1, sa, 0, 0, 0);
      __builtin_amdgcn_s_setprio(0);
      s[c] = sa;
    }
    // p = exp2(s), TRUNCATED to bf16; l accumulates the truncated value.
    // ldsp write: row q=lg*4+r, byte (c*16+lr)*2 ^ ((q&7)<<4)  (T2 involution)
#pragma unroll
    for (int c = 0; c < 4; ++c)
#pragma unroll
      for (int r = 0; r < 4; ++r) {
        union { float f; uint32_t u; } pv;
        pv.f = exp2f(s[c][r]);
        *(uint16_t*)((char*)&ldsp[wid][lg * 4 + r][0] +
                     (((c * 16 + lr) * 2) ^ (((lg * 4 + r) & 7) << 4)))
            = (uint16_t)(pv.u >> 16);
        pv.u &= 0xffff0000u;
        lsum[r] += pv.f;
      }
    // ordering fence: scalar u16 writes -> vector bf16x8 read, same wave
    asm volatile("" ::: "memory");
    __builtin_amdgcn_sched_barrier(0);
    // O += P V
    __builtin_amdgcn_s_setprio(1);
#pragma unroll
    for (int kk = 0; kk < 2; ++kk) {
      bf16x8 pf = *(const bf16x8*)(kk ? pr1 : pr0);
#pragma unroll
      for (int cd = 0; cd < 4; ++cd) {
        bf16x8 vf = *(const bf16x8*)(vbase + koff + (kk ? kb1 : kb0) + cd * 2048);
        acc[cd] = __builtin_amdgcn_mfma_f32_16x16x32_bf16(pf, vf, acc[cd], 0, 0, 0);
      }
    }
    __builtin_amdgcn_s_setprio(0);
    __syncthreads();   // next tile landed (had full compute to arrive);
    cur ^= 1;          // buf & ldsp WAR protected
  }
  // final l reduce (16-lane groups), drop the 63 phantom keys, normalize, write O
#pragma unroll
  for (int r = 0; r < 4; ++r) {
    float l = lsum[r];
    l += __shfl_xor(l, 1); l += __shfl_xor(l, 2);
    l += __shfl_xor(l, 4); l += __shfl_xor(l, 8);
    l -= 63.0f;
    const float inv = 1.0f / l;
    const int n = qrow0 + lg * 4 + r;
    size_t base = ((size_t)b * NN + n) * DIMF + h * HD;
#pragma unroll
    for (int cd = 0; cd < 4; ++cd)
      o_ws[base + cd * 16 + lr] = f2b(acc[cd][r] * inv);
  }
}

extern "C" void kernel_launch(void* const* d_in, const int* in_sizes, int n_in,
                              void* d_out, int out_size, void* d_ws, size_t ws_size,
                              hipStream_t stream) {
  const float* x      = (const float*)d_in[0];
  const float* wqkv   = (const float*)d_in[1];
  const float* wout   = (const float*)d_in[2];
  const float* bout   = (const float*)d_in[3];
  // d_in[4] = void_q: unused (void query row is dropped by the reference)
  const float* voidk  = (const float*)d_in[5];
  const float* voidv  = (const float*)d_in[6];
  const float* trace  = (const float*)d_in[7];
  const float* factor = (const float*)d_in[8];
  float* out = (float*)d_out;           // reference output dtype is FP32

  uint16_t* ws    = (uint16_t*)d_ws;
  uint16_t* x_bf  = ws;                       // 2*2048*1024  = 4,194,304 elems
  uint16_t* o_ws  = x_bf;                     // ALIAS: x_bf dead after gemm0
  uint16_t* wqkvT = x_bf  + 4194304;          // 3072*1024    = 3,145,728
  uint16_t* woutT = wqkvT + 3145728;          // 1024*1024    = 1,048,576
  uint16_t* q_ws  = woutT + 1048576;          // 2*16*2048*64 = 4,194,304
  uint16_t* k_ws  = q_ws  + 4194304;          // 2*16*2112*64 = 4,325,376
  uint16_t* vt_ws = k_ws  + 4325376;          // 4,325,376   (total ~42.5 MB)

  prep_k<<<dim3(8704), dim3(256), 0, stream>>>(x, x_bf, voidk, voidv, k_ws, vt_ws,
                                               wqkv, wqkvT, wout, woutT);
  gemm0_k<<<dim3(3072 / 128, 4096 / 128), dim3(256), 0, stream>>>(
      x_bf, wqkvT, 1024, q_ws, k_ws, vt_ws, trace, factor);
  attn_k<<<dim3(HEADS * BB, NN / 128), dim3(512), 0, stream>>>(
      q_ws, k_ws, vt_ws, o_ws);
  gemm1_k<<<dim3(1024 / 128, 4096 / 64), dim3(256), 0, stream>>>(
      o_ws, woutT, 1024, out, bout);
}

// Round 20
// 139.826 us; speedup vs baseline: 1.0041x; 1.0041x over previous
//
#include <hip/hip_runtime.h>
#include <stdint.h>

#define DIMF   1024
#define HEADS  16
#define HD     64
#define BB     2
#define NN     2048
#define NKP    2112   // 2049 keys padded to 33*64
#define NTILE  33

typedef __attribute__((ext_vector_type(8))) __bf16 bf16x8;
typedef __attribute__((ext_vector_type(4))) float  f32x4;

__device__ __forceinline__ float b2f(uint16_t h) {
  union { uint32_t u; float f; } v; v.u = ((uint32_t)h) << 16; return v.f;
}
__device__ __forceinline__ uint16_t f2b(float f) {
  union { float f; uint32_t u; } v; v.f = f;
  uint32_t r = v.u + 0x7FFFu + ((v.u >> 16) & 1u);
  return (uint16_t)(r >> 16);
}

// async global->LDS DMA, 16B per lane. LDS dest = wave-uniform base + lane*16.
__device__ __forceinline__ void gl_lds16(const void* g, void* l) {
  __builtin_amdgcn_global_load_lds(
      (const __attribute__((address_space(1))) void*)g,
      (__attribute__((address_space(3))) void*)l, 16, 0, 0);
}

// ---- merged preprocessing (single launch) — EXACT round-16 kernel ----
__global__ __launch_bounds__(256) void prep_k(const float* __restrict__ x,
                                              uint16_t* __restrict__ x_bf,
                                              const float* __restrict__ vk,
                                              const float* __restrict__ vv,
                                              uint16_t* __restrict__ k_ws,
                                              uint16_t* __restrict__ vt_ws,
                                              const float* __restrict__ wqkv,
                                              uint16_t* __restrict__ wqkvT,
                                              const float* __restrict__ wout,
                                              uint16_t* __restrict__ woutT) {
  __shared__ uint16_t tile[32][33];
  const int blk = blockIdx.x;
  if (blk < 4096) {
    int i = blk * 256 + threadIdx.x;             // < 1048576 float4s
    float4 v = *(const float4*)&x[(size_t)i * 4];
    uint16_t* d = x_bf + (size_t)i * 4;
    d[0] = f2b(v.x); d[1] = f2b(v.y); d[2] = f2b(v.z); d[3] = f2b(v.w);
  } else if (blk < 4608) {
    int idx = (blk - 4096) * 256 + threadIdx.x;  // 0 .. 131071
    int dd = idx & 63;
    int r  = (idx >> 6) & 63;      // padded key row 2048+r
    int bh = idx >> 12;            // 0..31
    int h  = bh & (HEADS - 1);
    uint16_t kv  = (r == 0) ? f2b(vk[h * HD + dd]) : (uint16_t)0;
    uint16_t vvv = (r == 0) ? f2b(vv[h * HD + dd]) : (uint16_t)0;
    k_ws[((size_t)bh * NKP + NN + r) * HD + dd]  = kv;
    vt_ws[((size_t)bh * HD + dd) * NKP + NN + r] = vvv;
  } else {
    int tb = blk - 4608;
    const float* src; uint16_t* dst; int N, bx, by;
    if (tb < 3072) { src = wqkv; dst = wqkvT; N = 3072; bx = (tb % 96) * 32; by = (tb / 96) * 32; }
    else { tb -= 3072; src = wout; dst = woutT; N = 1024; bx = (tb % 32) * 32; by = (tb / 32) * 32; }
    const int M = 1024;
    int xx = threadIdx.x & 31, y0 = (threadIdx.x >> 5) * 4;
#pragma unroll
    for (int i = 0; i < 4; ++i)
      tile[y0 + i][xx] = f2b(src[(size_t)(by + y0 + i) * N + bx + xx]);
    __syncthreads();
#pragma unroll
    for (int i = 0; i < 4; ++i)
      dst[(size_t)(bx + y0 + i) * M + by + xx] = tile[xx][y0 + i];
  }
}

// ------------- GEMM0: 128x128, BK=64, swizzled; Q pre-scaled (wave-uniform) -------------
__global__ __launch_bounds__(256) void gemm0_k(const uint16_t* __restrict__ A,
                                               const uint16_t* __restrict__ Bt,
                                               int K,
                                               uint16_t* __restrict__ o0,
                                               uint16_t* __restrict__ o1,
                                               uint16_t* __restrict__ o2,
                                               const float* __restrict__ trace,
                                               const float* __restrict__ factor) {
  __shared__ uint16_t lds_a[128][64];   // 16 KB, linear dest for global_load_lds
  __shared__ uint16_t lds_b[128][64];   // 16 KB
  const int m0 = blockIdx.y * 128, n0 = blockIdx.x * 128;
  const int tid = threadIdx.x, lane = tid & 63, wid = tid >> 6;
  const int wm = (wid >> 1) * 64, wn = (wid & 1) * 64;
  const int lr = lane & 15, lg = lane >> 4;

  const int rsw = (lr & 7) << 4;
  const int rc0 = (lg * 16) ^ rsw;
  const int rc1 = (64 + lg * 16) ^ rsw;

  f32x4 acc[4][4] = {};
  for (int k0 = 0; k0 < K; k0 += 64) {
    __syncthreads();
#pragma unroll
    for (int it = 0; it < 4; ++it) {
      const int chunk = wid * 4 + it;            // 0..15 (1 KiB each)
      const int o = chunk * 1024 + lane * 16;
      const int r = o >> 7, cb = o & 127;        // 128 B per row
      const int scb = cb ^ ((r & 7) << 4);       // pre-swizzled source col
      gl_lds16((const char*)&A[(size_t)(m0 + r) * K + k0] + scb,
               (char*)&lds_a[0][0] + chunk * 1024);
      gl_lds16((const char*)&Bt[(size_t)(n0 + r) * K + k0] + scb,
               (char*)&lds_b[0][0] + chunk * 1024);
    }
    __syncthreads();
    bf16x8 af[4][2], bf[4][2];
#pragma unroll
    for (int i = 0; i < 4; ++i) {
      const char* ra = (const char*)&lds_a[0][0] + (wm + i * 16 + lr) * 128;
      af[i][0] = *(const bf16x8*)(ra + rc0);
      af[i][1] = *(const bf16x8*)(ra + rc1);
    }
#pragma unroll
    for (int j = 0; j < 4; ++j) {
      const char* rb = (const char*)&lds_b[0][0] + (wn + j * 16 + lr) * 128;
      bf[j][0] = *(const bf16x8*)(rb + rc0);
      bf[j][1] = *(const bf16x8*)(rb + rc1);
    }
#pragma unroll
    for (int kk = 0; kk < 2; ++kk)
#pragma unroll
      for (int i = 0; i < 4; ++i)
#pragma unroll
        for (int j = 0; j < 4; ++j)
          acc[i][j] = __builtin_amdgcn_mfma_f32_16x16x32_bf16(af[i][kk], bf[j][kk],
                                                              acc[i][j], 0, 0, 0);
  }
  // which/h are uniform over this wave's 64-column span
  const int ngb    = n0 + wn;
  const int whichU = ngb >> 10;
  const int hU     = (ngb & (DIMF - 1)) >> 6;
  float qsW = 1.0f;
  if (whichU == 0)
    qsW = 0.04508422f / fmaxf(1.0f + fabsf(trace[hU]) * factor[hU], 1.0f);
#pragma unroll
  for (int i = 0; i < 4; ++i)
#pragma unroll
    for (int j = 0; j < 4; ++j)
#pragma unroll
      for (int r = 0; r < 4; ++r) {
        int mg = m0 + wm + i * 16 + lg * 4 + r;   // C row = m (m89 layout)
        int ng = n0 + wn + j * 16 + lr;            // C col = n
        int b = mg >> 11, n = mg & (NN - 1);
        int dd = ng & 63;
        int bh = b * HEADS + hU;
        float v = acc[i][j][r];
        if (whichU == 0)      o0[((size_t)bh * NN + n) * HD + dd] = f2b(v * qsW);
        else if (whichU == 1) o1[((size_t)bh * NKP + n) * HD + dd] = f2b(v);
        else                  o2[((size_t)bh * HD + dd) * NKP + n] = f2b(v);  // V^T
      }
}

// ------------- GEMM1 — EXACT round-16 kernel (BM=64, BN=128) -------------
__global__ __launch_bounds__(256) void gemm1_k(const uint16_t* __restrict__ A,
                                               const uint16_t* __restrict__ Bt,
                                               int K,
                                               float* __restrict__ fo,
                                               const float* __restrict__ bias) {
  __shared__ uint16_t lds_a[64][64];    // 8 KB
  __shared__ uint16_t lds_b[128][64];   // 16 KB
  const int m0 = blockIdx.y * 64, n0 = blockIdx.x * 128;
  const int tid = threadIdx.x, lane = tid & 63, wid = tid >> 6;
  const int wm = (wid >> 1) * 32, wn = (wid & 1) * 64;
  const int lr = lane & 15, lg = lane >> 4;

  const int rsw = (lr & 7) << 4;
  const int rc0 = (lg * 16) ^ rsw;
  const int rc1 = (64 + lg * 16) ^ rsw;

  f32x4 acc[2][4] = {};
  for (int k0 = 0; k0 < K; k0 += 64) {
    __syncthreads();
#pragma unroll
    for (int it = 0; it < 6; ++it) {
      const int c = wid * 6 + it;                // 0..23 (1 KiB each): 8 A + 16 B
      if (c < 8) {
        const int o = c * 1024 + lane * 16;
        const int r = o >> 7, cb = o & 127;
        const int scb = cb ^ ((r & 7) << 4);
        gl_lds16((const char*)&A[(size_t)(m0 + r) * K + k0] + scb,
                 (char*)&lds_a[0][0] + c * 1024);
      } else {
        const int o2 = (c - 8) * 1024 + lane * 16;
        const int r = o2 >> 7, cb = o2 & 127;
        const int scb = cb ^ ((r & 7) << 4);
        gl_lds16((const char*)&Bt[(size_t)(n0 + r) * K + k0] + scb,
                 (char*)&lds_b[0][0] + (c - 8) * 1024);
      }
    }
    __syncthreads();
    bf16x8 af[2][2], bf[4][2];
#pragma unroll
    for (int i = 0; i < 2; ++i) {
      const char* ra = (const char*)&lds_a[0][0] + (wm + i * 16 + lr) * 128;
      af[i][0] = *(const bf16x8*)(ra + rc0);
      af[i][1] = *(const bf16x8*)(ra + rc1);
    }
#pragma unroll
    for (int j = 0; j < 4; ++j) {
      const char* rb = (const char*)&lds_b[0][0] + (wn + j * 16 + lr) * 128;
      bf[j][0] = *(const bf16x8*)(rb + rc0);
      bf[j][1] = *(const bf16x8*)(rb + rc1);
    }
#pragma unroll
    for (int kk = 0; kk < 2; ++kk)
#pragma unroll
      for (int i = 0; i < 2; ++i)
#pragma unroll
        for (int j = 0; j < 4; ++j)
          acc[i][j] = __builtin_amdgcn_mfma_f32_16x16x32_bf16(af[i][kk], bf[j][kk],
                                                              acc[i][j], 0, 0, 0);
  }
#pragma unroll
  for (int i = 0; i < 2; ++i)
#pragma unroll
    for (int j = 0; j < 4; ++j)
#pragma unroll
      for (int r = 0; r < 4; ++r) {
        int mg = m0 + wm + i * 16 + lg * 4 + r;
        int ng = n0 + wn + j * 16 + lr;
        fo[(size_t)mg * DIMF + ng] = acc[i][j][r] + bias[ng];
      }
}

// ---- flash attention: EXACT round-18 kernel, ONE change: exp2f (Q pre-scaled) ----
// ldsp back to padded [8][16][72] (unswizzled, hoisted pr base — the 61.5 µs
// configuration). The only delta vs r18: p = exp2f(s) instead of
// __expf(s*scale) — 16 fewer v_mul/tile/thread, no address changes.
__global__ __launch_bounds__(512) void attn_k(const uint16_t* __restrict__ q_ws,
                                              const uint16_t* __restrict__ k_ws,
                                              const uint16_t* __restrict__ vt_ws,
                                              uint16_t* __restrict__ o_ws) {
  __shared__ uint16_t ldsk[2][64][64];   // [buf][key][d], swizzled cols (16 KB)
  __shared__ uint16_t ldsv[2][64][64];   // [buf][d][key], swizzled cols (16 KB)
  __shared__ uint16_t ldsp[8][16][72];   // per-wave P re-layout buffer (18.4 KB)
  const int bh = blockIdx.x;             // FASTEST dim -> XCD = bh%8 (L2 locality)
  const int qb = blockIdx.y;
  const int h = bh & (HEADS - 1), b = bh >> 4;
  const int tid = threadIdx.x, lane = tid & 63, wid = tid >> 6;  // wid 0..7
  const int lr = lane & 15, lg = lane >> 4;

  const int qrow0 = qb * 128 + wid * 16;
  const uint16_t* qrow = q_ws + ((size_t)bh * NN + qrow0 + lr) * HD;
  bf16x8 qf[2];
  qf[0] = *(const bf16x8*)(qrow + lg * 8);
  qf[1] = *(const bf16x8*)(qrow + 32 + lg * 8);

  // hoisted loop-invariant LDS read offsets (row = c*16+lr -> row&7 == lr&7)
  const int rsw = (lr & 7) << 4;
  const int kb0 = lr * 128 + ((lg * 16) ^ rsw);
  const int kb1 = lr * 128 + ((64 + lg * 16) ^ rsw);
  const char* kbase = (const char*)&ldsk[0][0][0];
  const char* vbase = (const char*)&ldsv[0][0][0];
  const char* pr = (const char*)&ldsp[wid][lr][lg * 8];

  f32x4 acc[4] = {};
  float lsum[4] = {0.f, 0.f, 0.f, 0.f};

#define STAGE(buf, t)                                                            \
  {                                                                              \
    const int t0_ = (t) * 64;                                                    \
    const int chunk = wid;                    /* 0..7 (1 KiB each) */            \
    const int o = chunk * 1024 + lane * 16;                                      \
    const int r = o >> 7, cb = o & 127;       /* 128 B per row */                \
    const int scb = cb ^ ((r & 7) << 4);      /* pre-swizzled source col */      \
    gl_lds16((const char*)&k_ws[((size_t)bh * NKP + t0_ + r) * HD] + scb,        \
             (char*)&ldsk[buf][0][0] + chunk * 1024);                            \
    gl_lds16((const char*)&vt_ws[((size_t)bh * HD + r) * NKP + t0_] + scb,       \
             (char*)&ldsv[buf][0][0] + chunk * 1024);                            \
  }

  STAGE(0, 0);
  __syncthreads();   // vmcnt(0) drained: tile 0 visible
  int cur = 0;

  for (int t = 0; t < NTILE; ++t) {
    const int tn = (t + 1 < NTILE) ? t + 1 : t;  // last iter: harmless restage
    STAGE(cur ^ 1, tn);                          // issue BEFORE compute

    const int koff = cur * 8192;                 // byte offset of current buffer

    // S = Q K^T (4 chunks of 16 keys); Q pre-scaled by scale*log2e
    f32x4 s[4];
#pragma unroll
    for (int c = 0; c < 4; ++c) {
      bf16x8 kf0 = *(const bf16x8*)(kbase + koff + kb0 + c * 2048);
      bf16x8 kf1 = *(const bf16x8*)(kbase + koff + kb1 + c * 2048);
      f32x4 sa = {};
      __builtin_amdgcn_s_setprio(1);
      sa = __builtin_amdgcn_mfma_f32_16x16x32_bf16(qf[0], kf0, sa, 0, 0, 0);
      sa = __builtin_amdgcn_mfma_f32_16x16x32_bf16(qf[1], kf1, sa, 0, 0, 0);
      __builtin_amdgcn_s_setprio(0);
      s[c] = sa;
    }
    // p = exp2(s), TRUNCATED to bf16; l accumulates the truncated value
#pragma unroll
    for (int c = 0; c < 4; ++c)
#pragma unroll
      for (int r = 0; r < 4; ++r) {
        union { float f; uint32_t u; } pv;
        pv.f = exp2f(s[c][r]);
        ldsp[wid][lg * 4 + r][c * 16 + lr] = (uint16_t)(pv.u >> 16);
        pv.u &= 0xffff0000u;
        lsum[r] += pv.f;
      }
    // ordering fence: scalar u16 writes -> vector bf16x8 read, same wave
    asm volatile("" ::: "memory");
    __builtin_amdgcn_sched_barrier(0);
    // O += P V
    __builtin_amdgcn_s_setprio(1);
#pragma unroll
    for (int kk = 0; kk < 2; ++kk) {
      bf16x8 pf = *(const bf16x8*)(pr + kk * 64);
#pragma unroll
      for (int cd = 0; cd < 4; ++cd) {
        bf16x8 vf = *(const bf16x8*)(vbase + koff + (kk ? kb1 : kb0) + cd * 2048);
        acc[cd] = __builtin_amdgcn_mfma_f32_16x16x32_bf16(pf, vf, acc[cd], 0, 0, 0);
      }
    }
    __builtin_amdgcn_s_setprio(0);
    __syncthreads();   // next tile landed (had full compute to arrive);
    cur ^= 1;          // buf & ldsp WAR protected
  }
  // final l reduce (16-lane groups), drop the 63 phantom keys, normalize, write O
#pragma unroll
  for (int r = 0; r < 4; ++r) {
    float l = lsum[r];
    l += __shfl_xor(l, 1); l += __shfl_xor(l, 2);
    l += __shfl_xor(l, 4); l += __shfl_xor(l, 8);
    l -= 63.0f;
    const float inv = 1.0f / l;
    const int n = qrow0 + lg * 4 + r;
    size_t base = ((size_t)b * NN + n) * DIMF + h * HD;
#pragma unroll
    for (int cd = 0; cd < 4; ++cd)
      o_ws[base + cd * 16 + lr] = f2b(acc[cd][r] * inv);
  }
}

extern "C" void kernel_launch(void* const* d_in, const int* in_sizes, int n_in,
                              void* d_out, int out_size, void* d_ws, size_t ws_size,
                              hipStream_t stream) {
  const float* x      = (const float*)d_in[0];
  const float* wqkv   = (const float*)d_in[1];
  const float* wout   = (const float*)d_in[2];
  const float* bout   = (const float*)d_in[3];
  // d_in[4] = void_q: unused (void query row is dropped by the reference)
  const float* voidk  = (const float*)d_in[5];
  const float* voidv  = (const float*)d_in[6];
  const float* trace  = (const float*)d_in[7];
  const float* factor = (const float*)d_in[8];
  float* out = (float*)d_out;           // reference output dtype is FP32

  uint16_t* ws    = (uint16_t*)d_ws;
  uint16_t* x_bf  = ws;                       // 2*2048*1024  = 4,194,304 elems
  uint16_t* o_ws  = x_bf;                     // ALIAS: x_bf dead after gemm0
  uint16_t* wqkvT = x_bf  + 4194304;          // 3072*1024    = 3,145,728
  uint16_t* woutT = wqkvT + 3145728;          // 1024*1024    = 1,048,576
  uint16_t* q_ws  = woutT + 1048576;          // 2*16*2048*64 = 4,194,304
  uint16_t* k_ws  = q_ws  + 4194304;          // 2*16*2112*64 = 4,325,376
  uint16_t* vt_ws = k_ws  + 4325376;          // 4,325,376   (total ~42.5 MB)

  prep_k<<<dim3(8704), dim3(256), 0, stream>>>(x, x_bf, voidk, voidv, k_ws, vt_ws,
                                               wqkv, wqkvT, wout, woutT);
  gemm0_k<<<dim3(3072 / 128, 4096 / 128), dim3(256), 0, stream>>>(
      x_bf, wqkvT, 1024, q_ws, k_ws, vt_ws, trace, factor);
  attn_k<<<dim3(HEADS * BB, NN / 128), dim3(512), 0, stream>>>(
      q_ws, k_ws, vt_ws, o_ws);
  gemm1_k<<<dim3(1024 / 128, 4096 / 64), dim3(256), 0, stream>>>(
      o_ws, woutT, 1024, out, bout);
}

// Round 21
// 129.200 us; speedup vs baseline: 1.0867x; 1.0822x over previous
//
#include <hip/hip_runtime.h>
#include <stdint.h>

#define DIMF   1024
#define HEADS  16
#define HD     64
#define BB     2
#define NN     2048
#define NKP    2112   // 2049 keys padded to 33*64
#define NTILE  33

typedef __attribute__((ext_vector_type(8))) __bf16 bf16x8;
typedef __attribute__((ext_vector_type(4))) float  f32x4;

__device__ __forceinline__ float b2f(uint16_t h) {
  union { uint32_t u; float f; } v; v.u = ((uint32_t)h) << 16; return v.f;
}
__device__ __forceinline__ uint16_t f2b(float f) {
  union { float f; uint32_t u; } v; v.f = f;
  uint32_t r = v.u + 0x7FFFu + ((v.u >> 16) & 1u);
  return (uint16_t)(r >> 16);
}

// async global->LDS DMA, 16B per lane. LDS dest = wave-uniform base + lane*16.
__device__ __forceinline__ void gl_lds16(const void* g, void* l) {
  __builtin_amdgcn_global_load_lds(
      (const __attribute__((address_space(1))) void*)g,
      (__attribute__((address_space(3))) void*)l, 16, 0, 0);
}

// ---- merged preprocessing (single launch) — EXACT round-16 kernel ----
__global__ __launch_bounds__(256) void prep_k(const float* __restrict__ x,
                                              uint16_t* __restrict__ x_bf,
                                              const float* __restrict__ vk,
                                              const float* __restrict__ vv,
                                              uint16_t* __restrict__ k_ws,
                                              uint16_t* __restrict__ vt_ws,
                                              const float* __restrict__ wqkv,
                                              uint16_t* __restrict__ wqkvT,
                                              const float* __restrict__ wout,
                                              uint16_t* __restrict__ woutT) {
  __shared__ uint16_t tile[32][33];
  const int blk = blockIdx.x;
  if (blk < 4096) {
    int i = blk * 256 + threadIdx.x;             // < 1048576 float4s
    float4 v = *(const float4*)&x[(size_t)i * 4];
    uint16_t* d = x_bf + (size_t)i * 4;
    d[0] = f2b(v.x); d[1] = f2b(v.y); d[2] = f2b(v.z); d[3] = f2b(v.w);
  } else if (blk < 4608) {
    int idx = (blk - 4096) * 256 + threadIdx.x;  // 0 .. 131071
    int dd = idx & 63;
    int r  = (idx >> 6) & 63;      // padded key row 2048+r
    int bh = idx >> 12;            // 0..31
    int h  = bh & (HEADS - 1);
    uint16_t kv  = (r == 0) ? f2b(vk[h * HD + dd]) : (uint16_t)0;
    uint16_t vvv = (r == 0) ? f2b(vv[h * HD + dd]) : (uint16_t)0;
    k_ws[((size_t)bh * NKP + NN + r) * HD + dd]  = kv;
    vt_ws[((size_t)bh * HD + dd) * NKP + NN + r] = vvv;
  } else {
    int tb = blk - 4608;
    const float* src; uint16_t* dst; int N, bx, by;
    if (tb < 3072) { src = wqkv; dst = wqkvT; N = 3072; bx = (tb % 96) * 32; by = (tb / 96) * 32; }
    else { tb -= 3072; src = wout; dst = woutT; N = 1024; bx = (tb % 32) * 32; by = (tb / 32) * 32; }
    const int M = 1024;
    int xx = threadIdx.x & 31, y0 = (threadIdx.x >> 5) * 4;
#pragma unroll
    for (int i = 0; i < 4; ++i)
      tile[y0 + i][xx] = f2b(src[(size_t)(by + y0 + i) * N + bx + xx]);
    __syncthreads();
#pragma unroll
    for (int i = 0; i < 4; ++i)
      dst[(size_t)(bx + y0 + i) * M + by + xx] = tile[xx][y0 + i];
  }
}

// ------------- GEMM0: 128x128, BK=64, swizzled; Q pre-scaled by PLAIN scale -------------
// qsW = (dim^-0.5)/temp, wave-uniform (2 scalar loads + 1 divide per thread).
// NO log2e factor: attn keeps the r18-proven fast-native __expf path.
__global__ __launch_bounds__(256) void gemm0_k(const uint16_t* __restrict__ A,
                                               const uint16_t* __restrict__ Bt,
                                               int K,
                                               uint16_t* __restrict__ o0,
                                               uint16_t* __restrict__ o1,
                                               uint16_t* __restrict__ o2,
                                               const float* __restrict__ trace,
                                               const float* __restrict__ factor) {
  __shared__ uint16_t lds_a[128][64];   // 16 KB, linear dest for global_load_lds
  __shared__ uint16_t lds_b[128][64];   // 16 KB
  const int m0 = blockIdx.y * 128, n0 = blockIdx.x * 128;
  const int tid = threadIdx.x, lane = tid & 63, wid = tid >> 6;
  const int wm = (wid >> 1) * 64, wn = (wid & 1) * 64;
  const int lr = lane & 15, lg = lane >> 4;

  const int rsw = (lr & 7) << 4;
  const int rc0 = (lg * 16) ^ rsw;
  const int rc1 = (64 + lg * 16) ^ rsw;

  f32x4 acc[4][4] = {};
  for (int k0 = 0; k0 < K; k0 += 64) {
    __syncthreads();
#pragma unroll
    for (int it = 0; it < 4; ++it) {
      const int chunk = wid * 4 + it;            // 0..15 (1 KiB each)
      const int o = chunk * 1024 + lane * 16;
      const int r = o >> 7, cb = o & 127;        // 128 B per row
      const int scb = cb ^ ((r & 7) << 4);       // pre-swizzled source col
      gl_lds16((const char*)&A[(size_t)(m0 + r) * K + k0] + scb,
               (char*)&lds_a[0][0] + chunk * 1024);
      gl_lds16((const char*)&Bt[(size_t)(n0 + r) * K + k0] + scb,
               (char*)&lds_b[0][0] + chunk * 1024);
    }
    __syncthreads();
    bf16x8 af[4][2], bf[4][2];
#pragma unroll
    for (int i = 0; i < 4; ++i) {
      const char* ra = (const char*)&lds_a[0][0] + (wm + i * 16 + lr) * 128;
      af[i][0] = *(const bf16x8*)(ra + rc0);
      af[i][1] = *(const bf16x8*)(ra + rc1);
    }
#pragma unroll
    for (int j = 0; j < 4; ++j) {
      const char* rb = (const char*)&lds_b[0][0] + (wn + j * 16 + lr) * 128;
      bf[j][0] = *(const bf16x8*)(rb + rc0);
      bf[j][1] = *(const bf16x8*)(rb + rc1);
    }
#pragma unroll
    for (int kk = 0; kk < 2; ++kk)
#pragma unroll
      for (int i = 0; i < 4; ++i)
#pragma unroll
        for (int j = 0; j < 4; ++j)
          acc[i][j] = __builtin_amdgcn_mfma_f32_16x16x32_bf16(af[i][kk], bf[j][kk],
                                                              acc[i][j], 0, 0, 0);
  }
  // which/h are uniform over this wave's 64-column span
  const int ngb    = n0 + wn;
  const int whichU = ngb >> 10;
  const int hU     = (ngb & (DIMF - 1)) >> 6;
  float qsW = 1.0f;
  if (whichU == 0)
    qsW = 0.03125f / fmaxf(1.0f + fabsf(trace[hU]) * factor[hU], 1.0f);
#pragma unroll
  for (int i = 0; i < 4; ++i)
#pragma unroll
    for (int j = 0; j < 4; ++j)
#pragma unroll
      for (int r = 0; r < 4; ++r) {
        int mg = m0 + wm + i * 16 + lg * 4 + r;   // C row = m (m89 layout)
        int ng = n0 + wn + j * 16 + lr;            // C col = n
        int b = mg >> 11, n = mg & (NN - 1);
        int dd = ng & 63;
        int bh = b * HEADS + hU;
        float v = acc[i][j][r];
        if (whichU == 0)      o0[((size_t)bh * NN + n) * HD + dd] = f2b(v * qsW);
        else if (whichU == 1) o1[((size_t)bh * NKP + n) * HD + dd] = f2b(v);
        else                  o2[((size_t)bh * HD + dd) * NKP + n] = f2b(v);  // V^T
      }
}

// ------------- GEMM1 — EXACT round-16 kernel (BM=64, BN=128) -------------
__global__ __launch_bounds__(256) void gemm1_k(const uint16_t* __restrict__ A,
                                               const uint16_t* __restrict__ Bt,
                                               int K,
                                               float* __restrict__ fo,
                                               const float* __restrict__ bias) {
  __shared__ uint16_t lds_a[64][64];    // 8 KB
  __shared__ uint16_t lds_b[128][64];   // 16 KB
  const int m0 = blockIdx.y * 64, n0 = blockIdx.x * 128;
  const int tid = threadIdx.x, lane = tid & 63, wid = tid >> 6;
  const int wm = (wid >> 1) * 32, wn = (wid & 1) * 64;
  const int lr = lane & 15, lg = lane >> 4;

  const int rsw = (lr & 7) << 4;
  const int rc0 = (lg * 16) ^ rsw;
  const int rc1 = (64 + lg * 16) ^ rsw;

  f32x4 acc[2][4] = {};
  for (int k0 = 0; k0 < K; k0 += 64) {
    __syncthreads();
#pragma unroll
    for (int it = 0; it < 6; ++it) {
      const int c = wid * 6 + it;                // 0..23 (1 KiB each): 8 A + 16 B
      if (c < 8) {
        const int o = c * 1024 + lane * 16;
        const int r = o >> 7, cb = o & 127;
        const int scb = cb ^ ((r & 7) << 4);
        gl_lds16((const char*)&A[(size_t)(m0 + r) * K + k0] + scb,
                 (char*)&lds_a[0][0] + c * 1024);
      } else {
        const int o2 = (c - 8) * 1024 + lane * 16;
        const int r = o2 >> 7, cb = o2 & 127;
        const int scb = cb ^ ((r & 7) << 4);
        gl_lds16((const char*)&Bt[(size_t)(n0 + r) * K + k0] + scb,
                 (char*)&lds_b[0][0] + (c - 8) * 1024);
      }
    }
    __syncthreads();
    bf16x8 af[2][2], bf[4][2];
#pragma unroll
    for (int i = 0; i < 2; ++i) {
      const char* ra = (const char*)&lds_a[0][0] + (wm + i * 16 + lr) * 128;
      af[i][0] = *(const bf16x8*)(ra + rc0);
      af[i][1] = *(const bf16x8*)(ra + rc1);
    }
#pragma unroll
    for (int j = 0; j < 4; ++j) {
      const char* rb = (const char*)&lds_b[0][0] + (wn + j * 16 + lr) * 128;
      bf[j][0] = *(const bf16x8*)(rb + rc0);
      bf[j][1] = *(const bf16x8*)(rb + rc1);
    }
#pragma unroll
    for (int kk = 0; kk < 2; ++kk)
#pragma unroll
      for (int i = 0; i < 2; ++i)
#pragma unroll
        for (int j = 0; j < 4; ++j)
          acc[i][j] = __builtin_amdgcn_mfma_f32_16x16x32_bf16(af[i][kk], bf[j][kk],
                                                              acc[i][j], 0, 0, 0);
  }
#pragma unroll
  for (int i = 0; i < 2; ++i)
#pragma unroll
    for (int j = 0; j < 4; ++j)
#pragma unroll
      for (int r = 0; r < 4; ++r) {
        int mg = m0 + wm + i * 16 + lg * 4 + r;
        int ng = n0 + wn + j * 16 + lr;
        fo[(size_t)mg * DIMF + ng] = acc[i][j][r] + bias[ng];
      }
}

// ---- flash attention: EXACT round-18 kernel (61.5 µs proven), ONE delta:
// p = __expf(s) with Q pre-scaled by plain scale (fast-native mul+v_exp path,
// minus the in-loop scale multiply). No address/layout/sync changes.
__global__ __launch_bounds__(512) void attn_k(const uint16_t* __restrict__ q_ws,
                                              const uint16_t* __restrict__ k_ws,
                                              const uint16_t* __restrict__ vt_ws,
                                              uint16_t* __restrict__ o_ws) {
  __shared__ uint16_t ldsk[2][64][64];   // [buf][key][d], swizzled cols (16 KB)
  __shared__ uint16_t ldsv[2][64][64];   // [buf][d][key], swizzled cols (16 KB)
  __shared__ uint16_t ldsp[8][16][72];   // per-wave P re-layout buffer (18.4 KB)
  const int bh = blockIdx.x;             // FASTEST dim -> XCD = bh%8 (L2 locality)
  const int qb = blockIdx.y;
  const int h = bh & (HEADS - 1), b = bh >> 4;
  const int tid = threadIdx.x, lane = tid & 63, wid = tid >> 6;  // wid 0..7
  const int lr = lane & 15, lg = lane >> 4;

  const int qrow0 = qb * 128 + wid * 16;
  const uint16_t* qrow = q_ws + ((size_t)bh * NN + qrow0 + lr) * HD;
  bf16x8 qf[2];
  qf[0] = *(const bf16x8*)(qrow + lg * 8);
  qf[1] = *(const bf16x8*)(qrow + 32 + lg * 8);

  // hoisted loop-invariant LDS read offsets (row = c*16+lr -> row&7 == lr&7)
  const int rsw = (lr & 7) << 4;
  const int kb0 = lr * 128 + ((lg * 16) ^ rsw);
  const int kb1 = lr * 128 + ((64 + lg * 16) ^ rsw);
  const char* kbase = (const char*)&ldsk[0][0][0];
  const char* vbase = (const char*)&ldsv[0][0][0];
  const char* pr = (const char*)&ldsp[wid][lr][lg * 8];

  f32x4 acc[4] = {};
  float lsum[4] = {0.f, 0.f, 0.f, 0.f};

#define STAGE(buf, t)                                                            \
  {                                                                              \
    const int t0_ = (t) * 64;                                                    \
    const int chunk = wid;                    /* 0..7 (1 KiB each) */            \
    const int o = chunk * 1024 + lane * 16;                                      \
    const int r = o >> 7, cb = o & 127;       /* 128 B per row */                \
    const int scb = cb ^ ((r & 7) << 4);      /* pre-swizzled source col */      \
    gl_lds16((const char*)&k_ws[((size_t)bh * NKP + t0_ + r) * HD] + scb,        \
             (char*)&ldsk[buf][0][0] + chunk * 1024);                            \
    gl_lds16((const char*)&vt_ws[((size_t)bh * HD + r) * NKP + t0_] + scb,       \
             (char*)&ldsv[buf][0][0] + chunk * 1024);                            \
  }

  STAGE(0, 0);
  __syncthreads();   // vmcnt(0) drained: tile 0 visible
  int cur = 0;

  for (int t = 0; t < NTILE; ++t) {
    const int tn = (t + 1 < NTILE) ? t + 1 : t;  // last iter: harmless restage
    STAGE(cur ^ 1, tn);                          // issue BEFORE compute

    const int koff = cur * 8192;                 // byte offset of current buffer

    // S = Q K^T (4 chunks of 16 keys); Q pre-scaled by (dim^-0.5 / temp)
    f32x4 s[4];
#pragma unroll
    for (int c = 0; c < 4; ++c) {
      bf16x8 kf0 = *(const bf16x8*)(kbase + koff + kb0 + c * 2048);
      bf16x8 kf1 = *(const bf16x8*)(kbase + koff + kb1 + c * 2048);
      f32x4 sa = {};
      __builtin_amdgcn_s_setprio(1);
      sa = __builtin_amdgcn_mfma_f32_16x16x32_bf16(qf[0], kf0, sa, 0, 0, 0);
      sa = __builtin_amdgcn_mfma_f32_16x16x32_bf16(qf[1], kf1, sa, 0, 0, 0);
      __builtin_amdgcn_s_setprio(0);
      s[c] = sa;
    }
    // p = __expf(s) (fast native: v_mul + v_exp), TRUNCATED to bf16;
    // l accumulates the truncated value (ratio-consistent)
#pragma unroll
    for (int c = 0; c < 4; ++c)
#pragma unroll
      for (int r = 0; r < 4; ++r) {
        union { float f; uint32_t u; } pv;
        pv.f = __expf(s[c][r]);
        ldsp[wid][lg * 4 + r][c * 16 + lr] = (uint16_t)(pv.u >> 16);
        pv.u &= 0xffff0000u;
        lsum[r] += pv.f;
      }
    // ordering fence: scalar u16 writes -> vector bf16x8 read, same wave
    asm volatile("" ::: "memory");
    __builtin_amdgcn_sched_barrier(0);
    // O += P V
    __builtin_amdgcn_s_setprio(1);
#pragma unroll
    for (int kk = 0; kk < 2; ++kk) {
      bf16x8 pf = *(const bf16x8*)(pr + kk * 64);
#pragma unroll
      for (int cd = 0; cd < 4; ++cd) {
        bf16x8 vf = *(const bf16x8*)(vbase + koff + (kk ? kb1 : kb0) + cd * 2048);
        acc[cd] = __builtin_amdgcn_mfma_f32_16x16x32_bf16(pf, vf, acc[cd], 0, 0, 0);
      }
    }
    __builtin_amdgcn_s_setprio(0);
    __syncthreads();   // next tile landed (had full compute to arrive);
    cur ^= 1;          // buf & ldsp WAR protected
  }
  // final l reduce (16-lane groups), drop the 63 phantom keys, normalize, write O
#pragma unroll
  for (int r = 0; r < 4; ++r) {
    float l = lsum[r];
    l += __shfl_xor(l, 1); l += __shfl_xor(l, 2);
    l += __shfl_xor(l, 4); l += __shfl_xor(l, 8);
    l -= 63.0f;
    const float inv = 1.0f / l;
    const int n = qrow0 + lg * 4 + r;
    size_t base = ((size_t)b * NN + n) * DIMF + h * HD;
#pragma unroll
    for (int cd = 0; cd < 4; ++cd)
      o_ws[base + cd * 16 + lr] = f2b(acc[cd][r] * inv);
  }
}

extern "C" void kernel_launch(void* const* d_in, const int* in_sizes, int n_in,
                              void* d_out, int out_size, void* d_ws, size_t ws_size,
                              hipStream_t stream) {
  const float* x      = (const float*)d_in[0];
  const float* wqkv   = (const float*)d_in[1];
  const float* wout   = (const float*)d_in[2];
  const float* bout   = (const float*)d_in[3];
  // d_in[4] = void_q: unused (void query row is dropped by the reference)
  const float* voidk  = (const float*)d_in[5];
  const float* voidv  = (const float*)d_in[6];
  const float* trace  = (const float*)d_in[7];
  const float* factor = (const float*)d_in[8];
  float* out = (float*)d_out;           // reference output dtype is FP32

  uint16_t* ws    = (uint16_t*)d_ws;
  uint16_t* x_bf  = ws;                       // 2*2048*1024  = 4,194,304 elems
  uint16_t* o_ws  = x_bf;                     // ALIAS: x_bf dead after gemm0
  uint16_t* wqkvT = x_bf  + 4194304;          // 3072*1024    = 3,145,728
  uint16_t* woutT = wqkvT + 3145728;          // 1024*1024    = 1,048,576
  uint16_t* q_ws  = woutT + 1048576;          // 2*16*2048*64 = 4,194,304
  uint16_t* k_ws  = q_ws  + 4194304;          // 2*16*2112*64 = 4,325,376
  uint16_t* vt_ws = k_ws  + 4325376;          // 4,325,376   (total ~42.5 MB)

  prep_k<<<dim3(8704), dim3(256), 0, stream>>>(x, x_bf, voidk, voidv, k_ws, vt_ws,
                                               wqkv, wqkvT, wout, woutT);
  gemm0_k<<<dim3(3072 / 128, 4096 / 128), dim3(256), 0, stream>>>(
      x_bf, wqkvT, 1024, q_ws, k_ws, vt_ws, trace, factor);
  attn_k<<<dim3(HEADS * BB, NN / 128), dim3(512), 0, stream>>>(
      q_ws, k_ws, vt_ws, o_ws);
  gemm1_k<<<dim3(1024 / 128, 4096 / 64), dim3(256), 0, stream>>>(
      o_ws, woutT, 1024, out, bout);
}